// Round 3
// baseline (565.430 us; speedup 1.0000x reference)
//
#include <hip/hip_runtime.h>
#include <hip/hip_bf16.h>

#define PI_F 3.14159265358979323846f
#define KPAD 264               // LDS activation row stride in fp16 (528 B, 16B-aligned)

typedef _Float16 h8 __attribute__((ext_vector_type(8)));
typedef _Float16 h4 __attribute__((ext_vector_type(4)));
typedef float f32x16 __attribute__((ext_vector_type(16)));

// ---- d_ws layout (fp16 elems). WT transposed: WT[n][k], k-contiguous. ----
#define OFF_DIN   0          // [256][96]
#define OFF_DHID  24576      // 6 x [256][256]
#define OFF_DOUT  417792     // [384][256]: n<256->Wd_out[k][n+1]; n==256->Wd_out[k][0]; else 0
#define OFF_CIN   516096     // [128][256]
#define OFF_CHID  548864     // 2 x [128][128]
#define OFF_COUT  581632     // [32][128]: n<3 -> Wc_out[k][n]; else 0
#define W_TOTAL   585728
// f32 biases appended after weights
#define B_DIN  0
#define B_DHID 256           // 6 x 256
#define B_FEAT 1792          // 384: n<256->bd_out[n+1]; n==256->bd_out[0]; else 0
#define B_CIN  2176          // 128
#define B_CHID 2304          // 2 x 128
#define B_TOTAL 2560
#define PREP_TOTAL (W_TOTAL + B_TOTAL)

__global__ void prep_kernel(const float* __restrict__ Wd_in,  const float* __restrict__ Wd_hid,
                            const float* __restrict__ Wd_out, const float* __restrict__ Wc_in,
                            const float* __restrict__ Wc_hid, const float* __restrict__ Wc_out,
                            const float* __restrict__ bd_in,  const float* __restrict__ bd_hid,
                            const float* __restrict__ bd_out, const float* __restrict__ bc_in,
                            const float* __restrict__ bc_hid,
                            _Float16* __restrict__ wdst, float* __restrict__ bdst)
{
    int i = blockIdx.x * 256 + threadIdx.x;
    if (i >= PREP_TOTAL) return;
    if (i < W_TOTAL) {
        float v = 0.f;
        if (i < OFF_DHID)      { int n = i / 96, k = i % 96; if (k < 75) v = Wd_in[k * 256 + n]; }
        else if (i < OFF_DOUT) { int j = i - OFF_DHID; int l = j / 65536, rem = j % 65536;
                                 int n = rem / 256, k = rem % 256; v = Wd_hid[(l * 256 + k) * 256 + n]; }
        else if (i < OFF_CIN)  { int j = i - OFF_DOUT; int n = j / 256, k = j % 256;
                                 if (n < 256) v = Wd_out[k * 257 + n + 1];
                                 else if (n == 256) v = Wd_out[k * 257]; }
        else if (i < OFF_CHID) { int j = i - OFF_CIN; int n = j / 256, k = j % 256; v = Wc_in[k * 128 + n]; }
        else if (i < OFF_COUT) { int j = i - OFF_CHID; int l = j / 16384, rem = j % 16384;
                                 int n = rem / 128, k = rem % 128; v = Wc_hid[(l * 128 + k) * 128 + n]; }
        else                   { int j = i - OFF_COUT; int n = j / 128, k = j % 128;
                                 if (n < 3) v = Wc_out[k * 3 + n]; }
        wdst[i] = (_Float16)v;
    } else {
        int b = i - W_TOTAL;
        float v = 0.f;
        if (b < B_DHID)      v = bd_in[b];
        else if (b < B_FEAT) v = bd_hid[b - B_DHID];
        else if (b < B_CIN)  { int n = b - B_FEAT;
                               if (n < 256) v = bd_out[n + 1]; else if (n == 256) v = bd_out[0]; }
        else if (b < B_CHID) v = bc_in[b - B_CIN];
        else                 v = bc_hid[b - B_CHID];
        bdst[b] = v;
    }
}

// One dense layer, 8 waves. Wave (r,c): rows r*64..+63 (mt=2), cols nbase..nbase+NT*32-1.
// A-operand = WT[n][k] (n rows), B-operand = At[m][k] (m cols).
// D[n][m]: col = lane&31 (m-local); row n-local = (reg&3)+8*(reg>>2)+4*lq.
// GUARD: skip writes for n0>=256; n0==256 goes to dval (density column).
template<int KT, int NT, bool RELU, int WK, bool GUARD>
__device__ __forceinline__ void dense(_Float16 (*At)[KPAD],
                                      const _Float16* __restrict__ WT,
                                      const float* __restrict__ bias,
                                      int rbase, int nbase, int lrow, int lq,
                                      float* dval)
{
    f32x16 acc[2][NT];
#pragma unroll
    for (int mt = 0; mt < 2; ++mt)
#pragma unroll
        for (int nt = 0; nt < NT; ++nt)
#pragma unroll
            for (int j = 0; j < 16; ++j) acc[mt][nt][j] = 0.f;

    const _Float16* wbase = WT + (size_t)(nbase + lrow) * WK + lq * 8;

#pragma unroll 2
    for (int kt = 0; kt < KT; ++kt) {
        const int koff = kt * 16 + lq * 8;
        h8 wf[NT];
#pragma unroll
        for (int nt = 0; nt < NT; ++nt)
            wf[nt] = *(const h8*)(wbase + (size_t)nt * 32 * WK + kt * 16);
        h8 af[2];
#pragma unroll
        for (int mt = 0; mt < 2; ++mt)
            af[mt] = *(const h8*)(&At[rbase + mt * 32 + lrow][koff]);
#pragma unroll
        for (int mt = 0; mt < 2; ++mt)
#pragma unroll
            for (int nt = 0; nt < NT; ++nt)
                acc[mt][nt] = __builtin_amdgcn_mfma_f32_32x32x16_f16(wf[nt], af[mt], acc[mt][nt], 0, 0, 0);
    }

    __syncthreads();   // all reads of At done

#pragma unroll
    for (int mt = 0; mt < 2; ++mt) {
        const int m = rbase + mt * 32 + lrow;
#pragma unroll
        for (int nt = 0; nt < NT; ++nt) {
#pragma unroll
            for (int p = 0; p < 4; ++p) {
                const int n0 = nbase + nt * 32 + p * 8 + lq * 4;
                if (GUARD && n0 >= 256) {
                    if (n0 == 256) dval[m] = acc[mt][nt][4 * p] + bias[256];
                } else {
                    float4 bv = *(const float4*)(bias + n0);
                    float a0 = acc[mt][nt][4 * p + 0] + bv.x;
                    float a1 = acc[mt][nt][4 * p + 1] + bv.y;
                    float a2 = acc[mt][nt][4 * p + 2] + bv.z;
                    float a3 = acc[mt][nt][4 * p + 3] + bv.w;
                    if (RELU) {
                        a0 = fmaxf(a0, 0.f); a1 = fmaxf(a1, 0.f);
                        a2 = fmaxf(a2, 0.f); a3 = fmaxf(a3, 0.f);
                    }
                    h4 hv;
                    hv[0] = (_Float16)a0; hv[1] = (_Float16)a1;
                    hv[2] = (_Float16)a2; hv[3] = (_Float16)a3;
                    *(h4*)(&At[m][n0]) = hv;
                }
            }
        }
    }
    __syncthreads();   // At ready for next layer
}

__global__ __launch_bounds__(512, 4)
void ffmlp_kernel(const float* __restrict__ mean, const float* __restrict__ cov,
                  const int* __restrict__ decayscale,
                  const _Float16* __restrict__ wws, const float* __restrict__ bws,
                  const float* __restrict__ bc_out,
                  float* __restrict__ out, int N)
{
    __shared__ __align__(16) _Float16 At[128][KPAD];
    __shared__ float dval[128];

    const int t = threadIdx.x;
    const int wid = t >> 6, lane = t & 63;
    const int c = wid & 3, r = wid >> 2;         // r in {0,1}, c in {0..3}
    const int lrow = lane & 31, lq = lane >> 5;
    const int rbase = r * 64;
    const int p0 = blockIdx.x * 128;

    // ---- Fourier embedding (fp32 math, fp16 store). 4 threads per point. ----
    {
        const int m = t >> 2, q = t & 3;
        const long pt = (long)p0 + m;
        float x0 = 0.f, x1 = 0.f, x2 = 0.f, v0 = 0.f, v1 = 0.f, v2 = 0.f;
        if (pt < N) {
            x0 = mean[pt * 3 + 0]; x1 = mean[pt * 3 + 1]; x2 = mean[pt * 3 + 2];
            v0 = cov[pt * 9 + 0];  v1 = cov[pt * 9 + 4];  v2 = cov[pt * 9 + 8];
        }
        const float dec = (float)(*decayscale);
        if (q == 0) {
            At[m][0] = (_Float16)x0; At[m][1] = (_Float16)x1; At[m][2] = (_Float16)x2;
            for (int k = 75; k < 80; ++k) At[m][k] = (_Float16)0.f;
        } else {
            for (int k = 75 + 5 * q; k < (q == 3 ? 96 : 80 + 5 * q); ++k) At[m][k] = (_Float16)0.f;
        }
        const float xs[3] = {x0, x1, x2}, vs[3] = {v0, v1, v2};
#pragma unroll
        for (int fi = 0; fi < 3; ++fi) {
            const int f = q * 3 + fi;
            const float fs = (float)(1 << f);
            const float wcl = fminf(fmaxf(dec - (float)f, 0.f), 1.f);
            const float win = 0.5f * (1.f - cosf(wcl * PI_F));
#pragma unroll
            for (int d = 0; d < 3; ++d) {
                const float xb = xs[d] * fs;
                const float att = expf(-0.5f * vs[d] * fs * fs) * win;
                float s, co;
                sincosf(xb, &s, &co);
                At[m][3 + 6 * f + d] = (_Float16)(s * att);
                At[m][6 + 6 * f + d] = (_Float16)(co * att);
            }
        }
    }
    __syncthreads();

    // ---- density MLP ----
    dense<6, 2, true, 96, false>(At, wws + OFF_DIN, bws + B_DIN, rbase, c * 64, lrow, lq, dval);
#pragma unroll 1
    for (int i = 0; i < 6; ++i)
        dense<16, 2, true, 256, false>(At, wws + OFF_DHID + i * 65536, bws + B_DHID + i * 256,
                                       rbase, c * 64, lrow, lq, dval);
    // FEAT: padded N=384 (cols 0..255 = features, col 256 = density, rest zero)
    dense<16, 3, false, 256, true>(At, wws + OFF_DOUT, bws + B_FEAT, rbase, c * 96, lrow, lq, dval);

    // ---- color MLP ----
    dense<16, 1, true, 256, false>(At, wws + OFF_CIN, bws + B_CIN, rbase, c * 32, lrow, lq, dval);
#pragma unroll 1
    for (int i = 0; i < 2; ++i)
        dense<8, 1, true, 128, false>(At, wws + OFF_CHID + i * 16384, bws + B_CHID + i * 128,
                                      rbase, c * 32, lrow, lq, dval);

    // ---- output layer: 128 -> 16 (rgb in rows 0..2 of W), waves with c==0 ----
    if (c == 0) {
        f32x16 acc[2];
#pragma unroll
        for (int mt = 0; mt < 2; ++mt)
#pragma unroll
            for (int j = 0; j < 16; ++j) acc[mt][j] = 0.f;
        const _Float16* wco = wws + OFF_COUT + (size_t)lrow * 128 + lq * 8;
#pragma unroll
        for (int kt = 0; kt < 8; ++kt) {
            const int koff = kt * 16 + lq * 8;
            h8 wf = *(const h8*)(wco + kt * 16);
#pragma unroll
            for (int mt = 0; mt < 2; ++mt) {
                h8 af = *(const h8*)(&At[rbase + mt * 32 + lrow][koff]);
                acc[mt] = __builtin_amdgcn_mfma_f32_32x32x16_f16(wf, af, acc[mt], 0, 0, 0);
            }
        }
        const float bc0 = bc_out[0], bc1 = bc_out[1], bc2 = bc_out[2];
        if (lq == 0) {
#pragma unroll
            for (int mt = 0; mt < 2; ++mt) {
                const int m = rbase + mt * 32 + lrow;
                const long pt = (long)p0 + m;
                if (pt < N) {
                    float4 o;
                    o.x = acc[mt][0] + bc0;
                    o.y = acc[mt][1] + bc1;
                    o.z = acc[mt][2] + bc2;
                    o.w = dval[m];
                    *(float4*)(out + pt * 4) = o;
                }
            }
        }
    }
}

extern "C" void kernel_launch(void* const* d_in, const int* in_sizes, int n_in,
                              void* d_out, int out_size, void* d_ws, size_t ws_size,
                              hipStream_t stream)
{
    const float* mean   = (const float*)d_in[0];
    const float* cov    = (const float*)d_in[1];
    const float* Wd_in  = (const float*)d_in[2];
    const float* bd_in  = (const float*)d_in[3];
    const float* Wd_hid = (const float*)d_in[4];
    const float* bd_hid = (const float*)d_in[5];
    const float* Wd_out = (const float*)d_in[6];
    const float* bd_out = (const float*)d_in[7];
    const float* Wc_in  = (const float*)d_in[8];
    const float* bc_in  = (const float*)d_in[9];
    const float* Wc_hid = (const float*)d_in[10];
    const float* bc_hid = (const float*)d_in[11];
    const float* Wc_out = (const float*)d_in[12];
    const float* bc_out = (const float*)d_in[13];
    const int*   decay  = (const int*)d_in[14];

    _Float16* wws = (_Float16*)d_ws;
    float*    bws = (float*)((char*)d_ws + (size_t)W_TOTAL * 2);

    const int N = in_sizes[0] / 3;     // 262144 points

    const int prep_blocks = (PREP_TOTAL + 255) / 256;
    prep_kernel<<<prep_blocks, 256, 0, stream>>>(Wd_in, Wd_hid, Wd_out, Wc_in, Wc_hid, Wc_out,
                                                 bd_in, bd_hid, bd_out, bc_in, bc_hid, wws, bws);

    const int blocks = (N + 127) / 128;
    ffmlp_kernel<<<blocks, 512, 0, stream>>>(mean, cov, decay, wws, bws, bc_out, (float*)d_out, N);
}

// Round 4
// 326.037 us; speedup vs baseline: 1.7343x; 1.7343x over previous
//
#include <hip/hip_runtime.h>
#include <hip/hip_bf16.h>

#define PI_F 3.14159265358979323846f
#define KPAD 260               // LDS act row stride in fp16 (520 B = 130 words, 2 mod 32 -> 2-way free)

typedef _Float16 h8 __attribute__((ext_vector_type(8)));
typedef _Float16 h4 __attribute__((ext_vector_type(4)));
typedef float f32x16 __attribute__((ext_vector_type(16)));

// ---- d_ws layout (fp16 elems) ----
// Weights pre-packed in per-lane MFMA fragment order:
//   block index (ntile*KT + kt) -> 1KB blob; lane l's h8 at byte l*16.
//   lane l fragment = W_T[n = ntile*32 + (l&31)][k = kt*16 + (l>>5)*8 + 0..7]
#define OFF_DIN   0          // KT=6,  8 ntiles  (K=96 pad, N=256)
#define OFF_DHID  24576      // 6 x KT=16, 8 ntiles
#define OFF_DOUT  417792     // KT=16, 12 ntiles (N=384: n<256->Wd_out[k][n+1]; n==256->Wd_out[k][0]; else 0)
#define OFF_CIN   516096     // KT=16, 4 ntiles  (N=128)
#define OFF_CHID  548864     // 2 x KT=8, 4 ntiles
#define OFF_COUT  581632     // KT=8,  1 ntile   (N=32: n<3 -> Wc_out[k][n]; else 0)
#define W_TOTAL   585728
// f32 biases appended after weights
#define B_DIN  0
#define B_DHID 256           // 6 x 256
#define B_FEAT 1792          // 384
#define B_CIN  2176          // 128
#define B_CHID 2304          // 2 x 128
#define B_TOTAL 2560
#define PREP_TOTAL (W_TOTAL + B_TOTAL)

__global__ void prep_kernel(const float* __restrict__ Wd_in,  const float* __restrict__ Wd_hid,
                            const float* __restrict__ Wd_out, const float* __restrict__ Wc_in,
                            const float* __restrict__ Wc_hid, const float* __restrict__ Wc_out,
                            const float* __restrict__ bd_in,  const float* __restrict__ bd_hid,
                            const float* __restrict__ bd_out, const float* __restrict__ bc_in,
                            const float* __restrict__ bc_hid,
                            _Float16* __restrict__ wdst, float* __restrict__ bdst)
{
    int i = blockIdx.x * 256 + threadIdx.x;
    if (i >= PREP_TOTAL) return;
    if (i < W_TOTAL) {
        float v = 0.f;
        int j, KT, n, k;
        // decompose packed index within a segment: j -> (tile, lane, e)
        #define DECODE(jj, KTv)  do { int frag = (jj) >> 3; int e = (jj) & 7;          \
                                      int lane = frag & 63; int tk = frag >> 6;         \
                                      int ntl = tk / (KTv); int kt = tk % (KTv);        \
                                      n = ntl * 32 + (lane & 31);                       \
                                      k = kt * 16 + (lane >> 5) * 8 + e; } while (0)
        if (i < OFF_DHID) {
            j = i; KT = 6; DECODE(j, KT);
            if (k < 75) v = Wd_in[k * 256 + n];
        } else if (i < OFF_DOUT) {
            j = i - OFF_DHID; int l = j >> 16; j &= 65535; KT = 16; DECODE(j, KT);
            v = Wd_hid[(l * 256 + k) * 256 + n];
        } else if (i < OFF_CIN) {
            j = i - OFF_DOUT; KT = 16; DECODE(j, KT);
            if (n < 256) v = Wd_out[k * 257 + n + 1];
            else if (n == 256) v = Wd_out[k * 257];
        } else if (i < OFF_CHID) {
            j = i - OFF_CIN; KT = 16; DECODE(j, KT);
            v = Wc_in[k * 128 + n];
        } else if (i < OFF_COUT) {
            j = i - OFF_CHID; int l = j >> 14; j &= 16383; KT = 8; DECODE(j, KT);
            v = Wc_hid[(l * 128 + k) * 128 + n];
        } else {
            j = i - OFF_COUT; KT = 8; DECODE(j, KT);
            if (n < 3) v = Wc_out[k * 3 + n];
        }
        #undef DECODE
        wdst[i] = (_Float16)v;
    } else {
        int b = i - W_TOTAL;
        float v = 0.f;
        if (b < B_DHID)      v = bd_in[b];
        else if (b < B_FEAT) v = bd_hid[b - B_DHID];
        else if (b < B_CIN)  { int n = b - B_FEAT;
                               if (n < 256) v = bd_out[n + 1]; else if (n == 256) v = bd_out[0]; }
        else if (b < B_CHID) v = bc_in[b - B_CIN];
        else                 v = bc_hid[b - B_CHID];
        bdst[b] = v;
    }
}

__device__ __forceinline__ h8 lds_read_h8(const _Float16* p)
{
    h4 lo = *(const h4*)(p);
    h4 hi = *(const h4*)(p + 4);
    return __builtin_shufflevector(lo, hi, 0, 1, 2, 3, 4, 5, 6, 7);
}

// One dense layer, 8 waves. Wave (r,c): rows r*64..+63 (mt=2), ntiles ntile0..ntile0+NT-1.
// A-operand = packed weight fragments (coalesced 1KB per (ntile,kt)).
// B-operand = At[m][k] from LDS (two ds_read_b64, 2-way free).
// D[n][m]: col = lane&31 (m-local); row n-local = (reg&3)+8*(reg>>2)+4*lq.
// GUARD: skip writes for n0>=256; n0==256 goes to dval (density column).
template<int KT, int NT, bool RELU, bool GUARD>
__device__ __forceinline__ void dense(_Float16 (*At)[KPAD],
                                      const _Float16* __restrict__ WP,
                                      const float* __restrict__ bias,
                                      int rbase, int ntile0, int lrow, int lq, int lane,
                                      float* dval)
{
    f32x16 acc[2][NT];
#pragma unroll
    for (int mt = 0; mt < 2; ++mt)
#pragma unroll
        for (int nt = 0; nt < NT; ++nt)
#pragma unroll
            for (int j = 0; j < 16; ++j) acc[mt][nt][j] = 0.f;

    const _Float16* wbase = WP + ((size_t)ntile0 * KT) * 512 + (size_t)lane * 8;

#pragma unroll 2
    for (int kt = 0; kt < KT; ++kt) {
        const int koff = kt * 16 + lq * 8;
        h8 wf[NT];
#pragma unroll
        for (int nt = 0; nt < NT; ++nt)
            wf[nt] = *(const h8*)(wbase + (size_t)(nt * KT + kt) * 512);
        h8 af[2];
#pragma unroll
        for (int mt = 0; mt < 2; ++mt)
            af[mt] = lds_read_h8(&At[rbase + mt * 32 + lrow][koff]);
#pragma unroll
        for (int mt = 0; mt < 2; ++mt)
#pragma unroll
            for (int nt = 0; nt < NT; ++nt)
                acc[mt][nt] = __builtin_amdgcn_mfma_f32_32x32x16_f16(wf[nt], af[mt], acc[mt][nt], 0, 0, 0);
    }

    __syncthreads();   // all reads of At done

#pragma unroll
    for (int mt = 0; mt < 2; ++mt) {
        const int m = rbase + mt * 32 + lrow;
#pragma unroll
        for (int nt = 0; nt < NT; ++nt) {
#pragma unroll
            for (int p = 0; p < 4; ++p) {
                const int n0 = (ntile0 + nt) * 32 + p * 8 + lq * 4;
                if (GUARD && n0 >= 256) {
                    if (n0 == 256) dval[m] = acc[mt][nt][4 * p] + bias[256];
                } else {
                    float4 bv = *(const float4*)(bias + n0);
                    float a0 = acc[mt][nt][4 * p + 0] + bv.x;
                    float a1 = acc[mt][nt][4 * p + 1] + bv.y;
                    float a2 = acc[mt][nt][4 * p + 2] + bv.z;
                    float a3 = acc[mt][nt][4 * p + 3] + bv.w;
                    if (RELU) {
                        a0 = fmaxf(a0, 0.f); a1 = fmaxf(a1, 0.f);
                        a2 = fmaxf(a2, 0.f); a3 = fmaxf(a3, 0.f);
                    }
                    h4 hv;
                    hv[0] = (_Float16)a0; hv[1] = (_Float16)a1;
                    hv[2] = (_Float16)a2; hv[3] = (_Float16)a3;
                    *(h4*)(&At[m][n0]) = hv;
                }
            }
        }
    }
    __syncthreads();   // At ready for next layer
}

__global__ __launch_bounds__(512, 4)
void ffmlp_kernel(const float* __restrict__ mean, const float* __restrict__ cov,
                  const int* __restrict__ decayscale,
                  const _Float16* __restrict__ wws, const float* __restrict__ bws,
                  const float* __restrict__ bc_out,
                  float* __restrict__ out, int N)
{
    __shared__ __align__(16) _Float16 At[128][KPAD];
    __shared__ float dval[128];

    const int t = threadIdx.x;
    const int wid = t >> 6, lane = t & 63;
    const int c = wid & 3, r = wid >> 2;         // r in {0,1}, c in {0..3}
    const int lrow = lane & 31, lq = lane >> 5;
    const int rbase = r * 64;
    const int p0 = blockIdx.x * 128;

    // ---- Fourier embedding (fp32 math, fp16 store). 4 threads per point. ----
    {
        const int m = t >> 2, q = t & 3;
        const long pt = (long)p0 + m;
        float x0 = 0.f, x1 = 0.f, x2 = 0.f, v0 = 0.f, v1 = 0.f, v2 = 0.f;
        if (pt < N) {
            x0 = mean[pt * 3 + 0]; x1 = mean[pt * 3 + 1]; x2 = mean[pt * 3 + 2];
            v0 = cov[pt * 9 + 0];  v1 = cov[pt * 9 + 4];  v2 = cov[pt * 9 + 8];
        }
        const float dec = (float)(*decayscale);
        if (q == 0) {
            At[m][0] = (_Float16)x0; At[m][1] = (_Float16)x1; At[m][2] = (_Float16)x2;
            for (int k = 75; k < 80; ++k) At[m][k] = (_Float16)0.f;
        } else {
            for (int k = 75 + 5 * q; k < (q == 3 ? 96 : 80 + 5 * q); ++k) At[m][k] = (_Float16)0.f;
        }
        const float xs[3] = {x0, x1, x2}, vs[3] = {v0, v1, v2};
#pragma unroll
        for (int fi = 0; fi < 3; ++fi) {
            const int f = q * 3 + fi;
            const float fs = (float)(1 << f);
            const float wcl = fminf(fmaxf(dec - (float)f, 0.f), 1.f);
            const float win = 0.5f * (1.f - cosf(wcl * PI_F));
#pragma unroll
            for (int d = 0; d < 3; ++d) {
                const float xb = xs[d] * fs;
                const float att = expf(-0.5f * vs[d] * fs * fs) * win;
                float s, co;
                sincosf(xb, &s, &co);
                At[m][3 + 6 * f + d] = (_Float16)(s * att);
                At[m][6 + 6 * f + d] = (_Float16)(co * att);
            }
        }
    }
    __syncthreads();

    // ---- density MLP ----
    dense<6, 2, true, false>(At, wws + OFF_DIN, bws + B_DIN, rbase, c * 2, lrow, lq, lane, dval);
#pragma unroll 1
    for (int i = 0; i < 6; ++i)
        dense<16, 2, true, false>(At, wws + OFF_DHID + i * 65536, bws + B_DHID + i * 256,
                                  rbase, c * 2, lrow, lq, lane, dval);
    // FEAT: padded N=384 (cols 0..255 = features, col 256 = density, rest zero)
    dense<16, 3, false, true>(At, wws + OFF_DOUT, bws + B_FEAT, rbase, c * 3, lrow, lq, lane, dval);

    // ---- color MLP ----
    dense<16, 1, true, false>(At, wws + OFF_CIN, bws + B_CIN, rbase, c, lrow, lq, lane, dval);
#pragma unroll 1
    for (int i = 0; i < 2; ++i)
        dense<8, 1, true, false>(At, wws + OFF_CHID + i * 16384, bws + B_CHID + i * 128,
                                 rbase, c, lrow, lq, lane, dval);

    // ---- output layer: 128 -> 16 (rgb in rows 0..2 of W), waves with c==0 ----
    if (c == 0) {
        f32x16 acc[2];
#pragma unroll
        for (int mt = 0; mt < 2; ++mt)
#pragma unroll
            for (int j = 0; j < 16; ++j) acc[mt][j] = 0.f;
        const _Float16* wco = wws + OFF_COUT + (size_t)lane * 8;
#pragma unroll
        for (int kt = 0; kt < 8; ++kt) {
            const int koff = kt * 16 + lq * 8;
            h8 wf = *(const h8*)(wco + (size_t)kt * 512);
#pragma unroll
            for (int mt = 0; mt < 2; ++mt) {
                h8 af = lds_read_h8(&At[rbase + mt * 32 + lrow][koff]);
                acc[mt] = __builtin_amdgcn_mfma_f32_32x32x16_f16(wf, af, acc[mt], 0, 0, 0);
            }
        }
        const float bc0 = bc_out[0], bc1 = bc_out[1], bc2 = bc_out[2];
        if (lq == 0) {
#pragma unroll
            for (int mt = 0; mt < 2; ++mt) {
                const int m = rbase + mt * 32 + lrow;
                const long pt = (long)p0 + m;
                if (pt < N) {
                    float4 o;
                    o.x = acc[mt][0] + bc0;
                    o.y = acc[mt][1] + bc1;
                    o.z = acc[mt][2] + bc2;
                    o.w = dval[m];
                    *(float4*)(out + pt * 4) = o;
                }
            }
        }
    }
}

extern "C" void kernel_launch(void* const* d_in, const int* in_sizes, int n_in,
                              void* d_out, int out_size, void* d_ws, size_t ws_size,
                              hipStream_t stream)
{
    const float* mean   = (const float*)d_in[0];
    const float* cov    = (const float*)d_in[1];
    const float* Wd_in  = (const float*)d_in[2];
    const float* bd_in  = (const float*)d_in[3];
    const float* Wd_hid = (const float*)d_in[4];
    const float* bd_hid = (const float*)d_in[5];
    const float* Wd_out = (const float*)d_in[6];
    const float* bd_out = (const float*)d_in[7];
    const float* Wc_in  = (const float*)d_in[8];
    const float* bc_in  = (const float*)d_in[9];
    const float* Wc_hid = (const float*)d_in[10];
    const float* bc_hid = (const float*)d_in[11];
    const float* Wc_out = (const float*)d_in[12];
    const float* bc_out = (const float*)d_in[13];
    const int*   decay  = (const int*)d_in[14];

    _Float16* wws = (_Float16*)d_ws;
    float*    bws = (float*)((char*)d_ws + (size_t)W_TOTAL * 2);

    const int N = in_sizes[0] / 3;     // 262144 points

    const int prep_blocks = (PREP_TOTAL + 255) / 256;
    prep_kernel<<<prep_blocks, 256, 0, stream>>>(Wd_in, Wd_hid, Wd_out, Wc_in, Wc_hid, Wc_out,
                                                 bd_in, bd_hid, bd_out, bc_in, bc_hid, wws, bws);

    const int blocks = (N + 127) / 128;
    ffmlp_kernel<<<blocks, 512, 0, stream>>>(mean, cov, decay, wws, bws, bc_out, (float*)d_out, N);
}

// Round 6
// 315.127 us; speedup vs baseline: 1.7943x; 1.0346x over previous
//
#include <hip/hip_runtime.h>
#include <hip/hip_bf16.h>

#define PI_F 3.14159265358979323846f
#define KPAD 260               // LDS act row stride in fp16 (520 B -> 2-way bank aliasing = free)

typedef _Float16 h8 __attribute__((ext_vector_type(8)));
typedef _Float16 h4 __attribute__((ext_vector_type(4)));
typedef _Float16 h2 __attribute__((ext_vector_type(2)));
typedef __fp16 fp16x2 __attribute__((ext_vector_type(2)));
typedef float f32x16 __attribute__((ext_vector_type(16)));

__device__ __forceinline__ h2 cvt_pk_h2(float a, float b)
{
    fp16x2 r = __builtin_amdgcn_cvt_pkrtz(a, b);
    return __builtin_bit_cast(h2, r);
}

// ---- d_ws: fp16 weights, fragment-packed ----
// block (ntile*KT + kt) -> 1KB blob; lane l's h8 at byte l*16:
//   W_T[n = ntile*32 + (l&31)][k = kt*16 + (l>>5)*8 + 0..7]
#define OFF_DIN   0          // 8 ntiles, KT=6   (K=96 pad, N=256)
#define OFF_DHID  24576      // 6 x (8 ntiles, KT=16)
#define OFF_FEAT  417792     // 8 ntiles, KT=16  (N=256: Wd_out[k][n+1])
#define OFF_CIN   483328     // 4 ntiles, KT=16  (N=128)
#define OFF_CHID  516096     // 2 x (4 ntiles, KT=8)
#define OFF_COUT  548864     // 1 ntile,  KT=8   (n<3 -> Wc_out[k][n]; else 0)
#define W_TOTAL   552960
// ---- f32 bias fragments after weights: per ntile 32 f32 = [lq][reg j],
//      value = bias[ntile*32 + (j&3) + 8*(j>>2) + 4*lq] ----
#define FB_DIN  0            // 256
#define FB_DHID 256          // 6 x 256
#define FB_FEAT 1792         // 256  (bd_out[n+1])
#define FB_CIN  2048         // 128
#define FB_CHID 2176         // 2 x 128
#define FB_WD0  2432         // 256: Wd_out[k*257]  (density weight column, plain order)
#define FB_BD0  2688         // 1:   bd_out[0]
#define B_TOTAL 2689
#define PREP_TOTAL (W_TOTAL + B_TOTAL)

__global__ void prep_kernel(const float* __restrict__ Wd_in,  const float* __restrict__ Wd_hid,
                            const float* __restrict__ Wd_out, const float* __restrict__ Wc_in,
                            const float* __restrict__ Wc_hid, const float* __restrict__ Wc_out,
                            const float* __restrict__ bd_in,  const float* __restrict__ bd_hid,
                            const float* __restrict__ bd_out, const float* __restrict__ bc_in,
                            const float* __restrict__ bc_hid,
                            _Float16* __restrict__ wdst, float* __restrict__ bdst)
{
    int i = blockIdx.x * 256 + threadIdx.x;
    if (i >= PREP_TOTAL) return;
    if (i < W_TOTAL) {
        float v = 0.f;
        int j, n, k;
        #define DECODE(jj, KTv)  do { int frag = (jj) >> 3; int e = (jj) & 7;          \
                                      int lane = frag & 63; int tk = frag >> 6;         \
                                      int ntl = tk / (KTv); int kt = tk % (KTv);        \
                                      n = ntl * 32 + (lane & 31);                       \
                                      k = kt * 16 + (lane >> 5) * 8 + e; } while (0)
        if (i < OFF_DHID) {
            j = i; DECODE(j, 6);
            if (k < 75) v = Wd_in[k * 256 + n];
        } else if (i < OFF_FEAT) {
            j = i - OFF_DHID; int l = j >> 16; j &= 65535; DECODE(j, 16);
            v = Wd_hid[(l * 256 + k) * 256 + n];
        } else if (i < OFF_CIN) {
            j = i - OFF_FEAT; DECODE(j, 16);
            v = Wd_out[k * 257 + n + 1];
        } else if (i < OFF_CHID) {
            j = i - OFF_CIN; DECODE(j, 16);
            v = Wc_in[k * 128 + n];
        } else if (i < OFF_COUT) {
            j = i - OFF_CHID; int l = j >> 14; j &= 16383; DECODE(j, 8);
            v = Wc_hid[(l * 128 + k) * 128 + n];
        } else {
            j = i - OFF_COUT; DECODE(j, 8);
            if (n < 3) v = Wc_out[k * 3 + n];
        }
        #undef DECODE
        wdst[i] = (_Float16)v;
    } else {
        int b = i - W_TOTAL;
        float v = 0.f;
        #define BDECODE(bb) int ntl = (bb) >> 5; int r5 = (bb) & 31;                   \
                            int lq = r5 >> 4, jj = r5 & 15;                            \
                            int n = ntl * 32 + (jj & 3) + 8 * (jj >> 2) + 4 * lq
        if (b < FB_DHID)      { BDECODE(b); v = bd_in[n]; }
        else if (b < FB_FEAT) { int b2 = b - FB_DHID; int l = b2 >> 8; int bb = b2 & 255;
                                BDECODE(bb); v = bd_hid[l * 256 + n]; }
        else if (b < FB_CIN)  { int bb = b - FB_FEAT; BDECODE(bb); v = bd_out[n + 1]; }
        else if (b < FB_CHID) { int bb = b - FB_CIN; BDECODE(bb); v = bc_in[n]; }
        else if (b < FB_WD0)  { int b2 = b - FB_CHID; int l = b2 >> 7; int bb = b2 & 127;
                                BDECODE(bb); v = bc_hid[l * 128 + n]; }
        else if (b < FB_BD0)  { int k = b - FB_WD0; v = Wd_out[k * 257]; }
        else                  { v = bd_out[0]; }
        #undef BDECODE
        bdst[b] = v;
    }
}

__device__ __forceinline__ h8 lds_read_h8(const _Float16* p)
{
    h4 lo = *(const h4*)(p);
    h4 hi = *(const h4*)(p + 4);
    return __builtin_shufflevector(lo, hi, 0, 1, 2, 3, 4, 5, 6, 7);
}

// One dense layer, 4 waves / 64 points. Wave c: ntiles c*NT .. c*NT+NT-1, all 64 rows (mt=2).
// acc initialized with fragment-packed bias. Packed-f16 epilogue.
// DDOT: before the barrier, compute density partial dot (k-slice [c*64, c*64+64)).
template<int KT, int NT, bool RELU, bool DDOT>
__device__ __forceinline__ void dense(_Float16 (*At)[KPAD],
                                      const _Float16* __restrict__ WP,
                                      const float* __restrict__ bfrag,
                                      const float* __restrict__ wd0,
                                      float (*dpart)[64],
                                      int c, int lrow, int lq, int lane)
{
    const int ntile0 = c * NT;
    f32x16 acc[2][NT];
#pragma unroll
    for (int nt = 0; nt < NT; ++nt) {
        f32x16 b = *(const f32x16*)(bfrag + (ntile0 + nt) * 32 + lq * 16);
        acc[0][nt] = b;
        acc[1][nt] = b;
    }

    const _Float16* wbase = WP + ((size_t)ntile0 * KT) * 512 + (size_t)lane * 8;

#pragma unroll 2
    for (int kt = 0; kt < KT; ++kt) {
        const int koff = kt * 16 + lq * 8;
        h8 wf[NT];
#pragma unroll
        for (int nt = 0; nt < NT; ++nt)
            wf[nt] = *(const h8*)(wbase + (size_t)(nt * KT + kt) * 512);
        h8 af[2];
#pragma unroll
        for (int mt = 0; mt < 2; ++mt)
            af[mt] = lds_read_h8(&At[mt * 32 + lrow][koff]);
        __builtin_amdgcn_s_setprio(1);
#pragma unroll
        for (int mt = 0; mt < 2; ++mt)
#pragma unroll
            for (int nt = 0; nt < NT; ++nt)
                acc[mt][nt] = __builtin_amdgcn_mfma_f32_32x32x16_f16(wf[nt], af[mt], acc[mt][nt], 0, 0, 0);
        __builtin_amdgcn_s_setprio(0);
    }

    if (DDOT) {
        // density partial: lane = point m, k-slice [c*64, c*64+64) of current h
        float s = 0.f;
        const float* w0 = wd0 + c * 64;
#pragma unroll
        for (int kk = 0; kk < 64; kk += 8) {
            h8 hv = lds_read_h8(&At[lane][c * 64 + kk]);
#pragma unroll
            for (int e = 0; e < 8; ++e)
                s = fmaf((float)hv[e], w0[kk + e], s);
        }
        dpart[c][lane] = s;
    }

    __syncthreads();   // all reads of At done

#pragma unroll
    for (int mt = 0; mt < 2; ++mt) {
        const int m = mt * 32 + lrow;
#pragma unroll
        for (int nt = 0; nt < NT; ++nt) {
#pragma unroll
            for (int p = 0; p < 4; ++p) {
                const int n0 = (ntile0 + nt) * 32 + p * 8 + lq * 4;
                h2 lo = cvt_pk_h2(acc[mt][nt][4 * p + 0], acc[mt][nt][4 * p + 1]);
                h2 hi = cvt_pk_h2(acc[mt][nt][4 * p + 2], acc[mt][nt][4 * p + 3]);
                h4 hv = __builtin_shufflevector(lo, hi, 0, 1, 2, 3);
                if (RELU) {
                    const h4 zero = {(_Float16)0, (_Float16)0, (_Float16)0, (_Float16)0};
                    hv = __builtin_elementwise_max(hv, zero);
                }
                *(h4*)(&At[m][n0]) = hv;
            }
        }
    }
    __syncthreads();   // At ready for next layer
}

__global__ __launch_bounds__(256, 4)
void ffmlp_kernel(const float* __restrict__ mean, const float* __restrict__ cov,
                  const int* __restrict__ decayscale,
                  const _Float16* __restrict__ wws, const float* __restrict__ bws,
                  const float* __restrict__ bc_out,
                  float* __restrict__ out, int N)
{
    __shared__ __align__(16) _Float16 At[64][KPAD];
    __shared__ float dpart[4][64];

    const int t = threadIdx.x;
    const int c = t >> 6, lane = t & 63;         // 4 waves, wave index = c
    const int lrow = lane & 31, lq = lane >> 5;
    const int p0 = blockIdx.x * 64;

    // ---- Fourier embedding (fp32 math, fp16 store). 4 threads per point. ----
    {
        const int m = t >> 2, q = t & 3;
        const long pt = (long)p0 + m;
        float x0 = 0.f, x1 = 0.f, x2 = 0.f, v0 = 0.f, v1 = 0.f, v2 = 0.f;
        if (pt < N) {
            x0 = mean[pt * 3 + 0]; x1 = mean[pt * 3 + 1]; x2 = mean[pt * 3 + 2];
            v0 = cov[pt * 9 + 0];  v1 = cov[pt * 9 + 4];  v2 = cov[pt * 9 + 8];
        }
        const float dec = (float)(*decayscale);
        if (q == 0) {
            At[m][0] = (_Float16)x0; At[m][1] = (_Float16)x1; At[m][2] = (_Float16)x2;
            for (int k = 75; k < 80; ++k) At[m][k] = (_Float16)0.f;
        } else {
            for (int k = 75 + 5 * q; k < (q == 3 ? 96 : 80 + 5 * q); ++k) At[m][k] = (_Float16)0.f;
        }
        const float xs[3] = {x0, x1, x2}, vs[3] = {v0, v1, v2};
#pragma unroll
        for (int fi = 0; fi < 3; ++fi) {
            const int f = q * 3 + fi;
            const float fs = (float)(1 << f);
            const float wcl = fminf(fmaxf(dec - (float)f, 0.f), 1.f);
            const float win = 0.5f * (1.f - cosf(wcl * PI_F));
#pragma unroll
            for (int d = 0; d < 3; ++d) {
                const float xb = xs[d] * fs;
                const float att = expf(-0.5f * vs[d] * fs * fs) * win;
                float s, co;
                sincosf(xb, &s, &co);
                At[m][3 + 6 * f + d] = (_Float16)(s * att);
                At[m][6 + 6 * f + d] = (_Float16)(co * att);
            }
        }
    }
    __syncthreads();

    // ---- density MLP ----
    dense<6, 2, true, false>(At, wws + OFF_DIN, bws + FB_DIN, bws, dpart, c, lrow, lq, lane);
#pragma unroll 1
    for (int i = 0; i < 6; ++i)
        dense<16, 2, true, false>(At, wws + OFF_DHID + i * 65536, bws + FB_DHID + i * 256,
                                  bws, dpart, c, lrow, lq, lane);
    // FEAT (no relu) + density partial dot on the pre-overwrite h
    dense<16, 2, false, true>(At, wws + OFF_FEAT, bws + FB_FEAT, bws + FB_WD0, dpart, c, lrow, lq, lane);

    // ---- color MLP ----
    dense<16, 1, true, false>(At, wws + OFF_CIN, bws + FB_CIN, bws, dpart, c, lrow, lq, lane);
#pragma unroll 1
    for (int i = 0; i < 2; ++i)
        dense<8, 1, true, false>(At, wws + OFF_CHID + i * 16384, bws + FB_CHID + i * 128,
                                 bws, dpart, c, lrow, lq, lane);

    // ---- output layer: 128 -> 16 (rgb cols 0..2), wave c==0 only ----
    if (c == 0) {
        f32x16 acc[2];
#pragma unroll
        for (int mt = 0; mt < 2; ++mt)
#pragma unroll
            for (int j = 0; j < 16; ++j) acc[mt][j] = 0.f;
        const _Float16* wco = wws + OFF_COUT + (size_t)lane * 8;
#pragma unroll
        for (int kt = 0; kt < 8; ++kt) {
            const int koff = kt * 16 + lq * 8;
            h8 wf = *(const h8*)(wco + (size_t)kt * 512);
#pragma unroll
            for (int mt = 0; mt < 2; ++mt) {
                h8 af = lds_read_h8(&At[mt * 32 + lrow][koff]);
                acc[mt] = __builtin_amdgcn_mfma_f32_32x32x16_f16(wf, af, acc[mt], 0, 0, 0);
            }
        }
        const float bc0 = bc_out[0], bc1 = bc_out[1], bc2 = bc_out[2];
        const float bd0 = bws[FB_BD0];
        if (lq == 0) {
#pragma unroll
            for (int mt = 0; mt < 2; ++mt) {
                const int m = mt * 32 + lrow;
                const long pt = (long)p0 + m;
                if (pt < N) {
                    float4 o;
                    o.x = acc[mt][0] + bc0;
                    o.y = acc[mt][1] + bc1;
                    o.z = acc[mt][2] + bc2;
                    o.w = dpart[0][m] + dpart[1][m] + dpart[2][m] + dpart[3][m] + bd0;
                    *(float4*)(out + pt * 4) = o;
                }
            }
        }
    }
}

extern "C" void kernel_launch(void* const* d_in, const int* in_sizes, int n_in,
                              void* d_out, int out_size, void* d_ws, size_t ws_size,
                              hipStream_t stream)
{
    const float* mean   = (const float*)d_in[0];
    const float* cov    = (const float*)d_in[1];
    const float* Wd_in  = (const float*)d_in[2];
    const float* bd_in  = (const float*)d_in[3];
    const float* Wd_hid = (const float*)d_in[4];
    const float* bd_hid = (const float*)d_in[5];
    const float* Wd_out = (const float*)d_in[6];
    const float* bd_out = (const float*)d_in[7];
    const float* Wc_in  = (const float*)d_in[8];
    const float* bc_in  = (const float*)d_in[9];
    const float* Wc_hid = (const float*)d_in[10];
    const float* bc_hid = (const float*)d_in[11];
    const float* Wc_out = (const float*)d_in[12];
    const float* bc_out = (const float*)d_in[13];
    const int*   decay  = (const int*)d_in[14];

    _Float16* wws = (_Float16*)d_ws;
    float*    bws = (float*)((char*)d_ws + (size_t)W_TOTAL * 2);

    const int N = in_sizes[0] / 3;     // 262144 points

    const int prep_blocks = (PREP_TOTAL + 255) / 256;
    prep_kernel<<<prep_blocks, 256, 0, stream>>>(Wd_in, Wd_hid, Wd_out, Wc_in, Wc_hid, Wc_out,
                                                 bd_in, bd_hid, bd_out, bc_in, bc_hid, wws, bws);

    const int blocks = (N + 63) / 64;
    ffmlp_kernel<<<blocks, 256, 0, stream>>>(mean, cov, decay, wws, bws, bc_out, (float*)d_out, N);
}

// Round 7
// 307.066 us; speedup vs baseline: 1.8414x; 1.0263x over previous
//
#include <hip/hip_runtime.h>
#include <hip/hip_bf16.h>

#define PI_F 3.14159265358979323846f
#define KPAD 260               // LDS act row stride in fp16 (520 B -> 2-way bank aliasing = free)

typedef _Float16 h8 __attribute__((ext_vector_type(8)));
typedef _Float16 h4 __attribute__((ext_vector_type(4)));
typedef _Float16 h2 __attribute__((ext_vector_type(2)));
typedef __fp16 fp16x2 __attribute__((ext_vector_type(2)));
typedef float f32x16 __attribute__((ext_vector_type(16)));

__device__ __forceinline__ h2 cvt_pk_h2(float a, float b)
{
    fp16x2 r = __builtin_amdgcn_cvt_pkrtz(a, b);
    return __builtin_bit_cast(h2, r);
}

// ---- d_ws: fp16 weights, fragment-packed ----
// block (ntile*KT + kt) -> 1KB blob; lane l's h8 at byte l*16:
//   W_T[n = ntile*32 + (l&31)][k = kt*16 + (l>>5)*8 + 0..7]
#define OFF_DIN   0          // 8 ntiles, KT=6   (K=96 pad, N=256)
#define OFF_DHID  24576      // 6 x (8 ntiles, KT=16)
#define OFF_FEAT  417792     // 8 ntiles, KT=16  (N=256: Wd_out[k][n+1])
#define OFF_CIN   483328     // 4 ntiles, KT=16  (N=128)
#define OFF_CHID  516096     // 2 x (4 ntiles, KT=8)
#define OFF_COUT  548864     // 1 ntile,  KT=8   (n<3 -> Wc_out[k][n]; else 0)
#define W_TOTAL   552960
// ---- f32 bias fragments after weights: per ntile 32 f32 = [lq][reg j],
//      value = bias[ntile*32 + (j&3) + 8*(j>>2) + 4*lq] ----
#define FB_DIN  0            // 256
#define FB_DHID 256          // 6 x 256
#define FB_FEAT 1792         // 256  (bd_out[n+1])
#define FB_CIN  2048         // 128
#define FB_CHID 2176         // 2 x 128
#define FB_WD0  2432         // 256: Wd_out[k*257]  (density weight column, plain order)
#define FB_BD0  2688         // 1:   bd_out[0]
#define B_TOTAL 2689
#define PREP_TOTAL (W_TOTAL + B_TOTAL)

__global__ void prep_kernel(const float* __restrict__ Wd_in,  const float* __restrict__ Wd_hid,
                            const float* __restrict__ Wd_out, const float* __restrict__ Wc_in,
                            const float* __restrict__ Wc_hid, const float* __restrict__ Wc_out,
                            const float* __restrict__ bd_in,  const float* __restrict__ bd_hid,
                            const float* __restrict__ bd_out, const float* __restrict__ bc_in,
                            const float* __restrict__ bc_hid,
                            _Float16* __restrict__ wdst, float* __restrict__ bdst)
{
    int i = blockIdx.x * 256 + threadIdx.x;
    if (i >= PREP_TOTAL) return;
    if (i < W_TOTAL) {
        float v = 0.f;
        int j, n, k;
        #define DECODE(jj, KTv)  do { int frag = (jj) >> 3; int e = (jj) & 7;          \
                                      int lane = frag & 63; int tk = frag >> 6;         \
                                      int ntl = tk / (KTv); int kt = tk % (KTv);        \
                                      n = ntl * 32 + (lane & 31);                       \
                                      k = kt * 16 + (lane >> 5) * 8 + e; } while (0)
        if (i < OFF_DHID) {
            j = i; DECODE(j, 6);
            if (k < 75) v = Wd_in[k * 256 + n];
        } else if (i < OFF_FEAT) {
            j = i - OFF_DHID; int l = j >> 16; j &= 65535; DECODE(j, 16);
            v = Wd_hid[(l * 256 + k) * 256 + n];
        } else if (i < OFF_CIN) {
            j = i - OFF_FEAT; DECODE(j, 16);
            v = Wd_out[k * 257 + n + 1];
        } else if (i < OFF_CHID) {
            j = i - OFF_CIN; DECODE(j, 16);
            v = Wc_in[k * 128 + n];
        } else if (i < OFF_COUT) {
            j = i - OFF_CHID; int l = j >> 14; j &= 16383; DECODE(j, 8);
            v = Wc_hid[(l * 128 + k) * 128 + n];
        } else {
            j = i - OFF_COUT; DECODE(j, 8);
            if (n < 3) v = Wc_out[k * 3 + n];
        }
        #undef DECODE
        wdst[i] = (_Float16)v;
    } else {
        int b = i - W_TOTAL;
        float v = 0.f;
        #define BDECODE(bb) int ntl = (bb) >> 5; int r5 = (bb) & 31;                   \
                            int lq = r5 >> 4, jj = r5 & 15;                            \
                            int n = ntl * 32 + (jj & 3) + 8 * (jj >> 2) + 4 * lq
        if (b < FB_DHID)      { BDECODE(b); v = bd_in[n]; }
        else if (b < FB_FEAT) { int b2 = b - FB_DHID; int l = b2 >> 8; int bb = b2 & 255;
                                BDECODE(bb); v = bd_hid[l * 256 + n]; }
        else if (b < FB_CIN)  { int bb = b - FB_FEAT; BDECODE(bb); v = bd_out[n + 1]; }
        else if (b < FB_CHID) { int bb = b - FB_CIN; BDECODE(bb); v = bc_in[n]; }
        else if (b < FB_WD0)  { int b2 = b - FB_CHID; int l = b2 >> 7; int bb = b2 & 127;
                                BDECODE(bb); v = bc_hid[l * 128 + n]; }
        else if (b < FB_BD0)  { int k = b - FB_WD0; v = Wd_out[k * 257]; }
        else                  { v = bd_out[0]; }
        #undef BDECODE
        bdst[b] = v;
    }
}

__device__ __forceinline__ h8 lds_read_h8(const _Float16* p)
{
    h4 lo = *(const h4*)(p);
    h4 hi = *(const h4*)(p + 4);
    return __builtin_shufflevector(lo, hi, 0, 1, 2, 3, 4, 5, 6, 7);
}

// One dense layer. 4 waves, wave (r,c): r -> rows rbase..rbase+63 (2 mtiles),
// c -> ntiles ntile0..ntile0+NT-1. 128 points per block.
// acc initialized with fragment-packed bias. Packed-f16 epilogue.
// DDOT: before the barrier, density partial dot, k-slice [wid*64, +64), m = lane, lane+64.
template<int KT, int NT, bool RELU, bool DDOT>
__device__ __forceinline__ void dense(_Float16 (*At)[KPAD],
                                      const _Float16* __restrict__ WP,
                                      const float* __restrict__ bfrag,
                                      const float* __restrict__ wd0,
                                      float (*dpart)[128],
                                      int rbase, int ntile0, int wid,
                                      int lrow, int lq, int lane)
{
    f32x16 acc[2][NT];
#pragma unroll
    for (int nt = 0; nt < NT; ++nt) {
        f32x16 b = *(const f32x16*)(bfrag + (ntile0 + nt) * 32 + lq * 16);
        acc[0][nt] = b;
        acc[1][nt] = b;
    }

    const _Float16* wbase = WP + ((size_t)ntile0 * KT) * 512 + (size_t)lane * 8;

#pragma unroll 2
    for (int kt = 0; kt < KT; ++kt) {
        const int koff = kt * 16 + lq * 8;
        h8 wf[NT];
#pragma unroll
        for (int nt = 0; nt < NT; ++nt)
            wf[nt] = *(const h8*)(wbase + (size_t)(nt * KT + kt) * 512);
        h8 af[2];
#pragma unroll
        for (int mt = 0; mt < 2; ++mt)
            af[mt] = lds_read_h8(&At[rbase + mt * 32 + lrow][koff]);
        __builtin_amdgcn_s_setprio(1);
#pragma unroll
        for (int mt = 0; mt < 2; ++mt)
#pragma unroll
            for (int nt = 0; nt < NT; ++nt)
                acc[mt][nt] = __builtin_amdgcn_mfma_f32_32x32x16_f16(wf[nt], af[mt], acc[mt][nt], 0, 0, 0);
        __builtin_amdgcn_s_setprio(0);
    }

    if (DDOT) {
        // density partial: k-slice [wid*64, +64) of current h, for m = lane and lane+64
        const float* w0 = wd0 + wid * 64;
#pragma unroll
        for (int m2 = 0; m2 < 2; ++m2) {
            const int m = lane + m2 * 64;
            float s = 0.f;
#pragma unroll
            for (int kk = 0; kk < 64; kk += 8) {
                h8 hv = lds_read_h8(&At[m][wid * 64 + kk]);
#pragma unroll
                for (int e = 0; e < 8; ++e)
                    s = fmaf((float)hv[e], w0[kk + e], s);
            }
            dpart[wid][m] = s;
        }
    }

    __syncthreads();   // all reads of At done

#pragma unroll
    for (int mt = 0; mt < 2; ++mt) {
        const int m = rbase + mt * 32 + lrow;
#pragma unroll
        for (int nt = 0; nt < NT; ++nt) {
#pragma unroll
            for (int p = 0; p < 4; ++p) {
                const int n0 = (ntile0 + nt) * 32 + p * 8 + lq * 4;
                h2 lo = cvt_pk_h2(acc[mt][nt][4 * p + 0], acc[mt][nt][4 * p + 1]);
                h2 hi = cvt_pk_h2(acc[mt][nt][4 * p + 2], acc[mt][nt][4 * p + 3]);
                h4 hv = __builtin_shufflevector(lo, hi, 0, 1, 2, 3);
                if (RELU) {
                    const h4 zero = {(_Float16)0, (_Float16)0, (_Float16)0, (_Float16)0};
                    hv = __builtin_elementwise_max(hv, zero);
                }
                *(h4*)(&At[m][n0]) = hv;
            }
        }
    }
    __syncthreads();   // At ready for next layer
}

__global__ __launch_bounds__(256, 2)
void ffmlp_kernel(const float* __restrict__ mean, const float* __restrict__ cov,
                  const int* __restrict__ decayscale,
                  const _Float16* __restrict__ wws, const float* __restrict__ bws,
                  const float* __restrict__ bc_out,
                  float* __restrict__ out, int N)
{
    __shared__ __align__(16) _Float16 At[128][KPAD];
    __shared__ float dpart[4][128];

    const int t = threadIdx.x;
    const int wid = t >> 6, lane = t & 63;       // 4 waves
    const int r = wid >> 1, c = wid & 1;         // r: row half, c: ntile half
    const int lrow = lane & 31, lq = lane >> 5;
    const int rbase = r * 64;
    const int p0 = blockIdx.x * 128;

    // ---- Fourier embedding (fp32 math, fp16 store). 2 threads per point. ----
    {
        const int m = t >> 1, hf = t & 1;
        const long pt = (long)p0 + m;
        float x0 = 0.f, x1 = 0.f, x2 = 0.f, v0 = 0.f, v1 = 0.f, v2 = 0.f;
        if (pt < N) {
            x0 = mean[pt * 3 + 0]; x1 = mean[pt * 3 + 1]; x2 = mean[pt * 3 + 2];
            v0 = cov[pt * 9 + 0];  v1 = cov[pt * 9 + 4];  v2 = cov[pt * 9 + 8];
        }
        const float dec = (float)(*decayscale);
        if (hf == 0) {
            At[m][0] = (_Float16)x0; At[m][1] = (_Float16)x1; At[m][2] = (_Float16)x2;
            for (int k = 75; k < 86; ++k) At[m][k] = (_Float16)0.f;
        } else {
            for (int k = 86; k < 96; ++k) At[m][k] = (_Float16)0.f;
        }
        const float xs[3] = {x0, x1, x2}, vs[3] = {v0, v1, v2};
#pragma unroll
        for (int fi = 0; fi < 6; ++fi) {
            const int f = hf * 6 + fi;
            const float fs = (float)(1 << f);
            const float wcl = fminf(fmaxf(dec - (float)f, 0.f), 1.f);
            const float win = 0.5f * (1.f - cosf(wcl * PI_F));
#pragma unroll
            for (int d = 0; d < 3; ++d) {
                const float xb = xs[d] * fs;
                const float att = expf(-0.5f * vs[d] * fs * fs) * win;
                float s, co;
                sincosf(xb, &s, &co);
                At[m][3 + 6 * f + d] = (_Float16)(s * att);
                At[m][6 + 6 * f + d] = (_Float16)(co * att);
            }
        }
    }
    __syncthreads();

    // ---- density MLP ----
    dense<6, 4, true, false>(At, wws + OFF_DIN, bws + FB_DIN, bws, dpart,
                             rbase, c * 4, wid, lrow, lq, lane);
#pragma unroll 1
    for (int i = 0; i < 6; ++i)
        dense<16, 4, true, false>(At, wws + OFF_DHID + i * 65536, bws + FB_DHID + i * 256,
                                  bws, dpart, rbase, c * 4, wid, lrow, lq, lane);
    // FEAT (no relu) + density partial dot on the pre-overwrite h
    dense<16, 4, false, true>(At, wws + OFF_FEAT, bws + FB_FEAT, bws + FB_WD0, dpart,
                              rbase, c * 4, wid, lrow, lq, lane);

    // ---- color MLP ----
    dense<16, 2, true, false>(At, wws + OFF_CIN, bws + FB_CIN, bws, dpart,
                              rbase, c * 2, wid, lrow, lq, lane);
#pragma unroll 1
    for (int i = 0; i < 2; ++i)
        dense<8, 2, true, false>(At, wws + OFF_CHID + i * 16384, bws + FB_CHID + i * 128,
                                 bws, dpart, rbase, c * 2, wid, lrow, lq, lane);

    // ---- output layer: 128 -> 16 (rgb cols 0..2), c==0 waves (r covers m-half) ----
    if (c == 0) {
        f32x16 acc[2];
#pragma unroll
        for (int mt = 0; mt < 2; ++mt)
#pragma unroll
            for (int j = 0; j < 16; ++j) acc[mt][j] = 0.f;
        const _Float16* wco = wws + OFF_COUT + (size_t)lane * 8;
#pragma unroll
        for (int kt = 0; kt < 8; ++kt) {
            const int koff = kt * 16 + lq * 8;
            h8 wf = *(const h8*)(wco + (size_t)kt * 512);
#pragma unroll
            for (int mt = 0; mt < 2; ++mt) {
                h8 af = lds_read_h8(&At[rbase + mt * 32 + lrow][koff]);
                acc[mt] = __builtin_amdgcn_mfma_f32_32x32x16_f16(wf, af, acc[mt], 0, 0, 0);
            }
        }
        const float bc0 = bc_out[0], bc1 = bc_out[1], bc2 = bc_out[2];
        const float bd0 = bws[FB_BD0];
        if (lq == 0) {
#pragma unroll
            for (int mt = 0; mt < 2; ++mt) {
                const int m = rbase + mt * 32 + lrow;
                const long pt = (long)p0 + m;
                if (pt < N) {
                    float4 o;
                    o.x = acc[mt][0] + bc0;
                    o.y = acc[mt][1] + bc1;
                    o.z = acc[mt][2] + bc2;
                    o.w = dpart[0][m] + dpart[1][m] + dpart[2][m] + dpart[3][m] + bd0;
                    *(float4*)(out + pt * 4) = o;
                }
            }
        }
    }
}

extern "C" void kernel_launch(void* const* d_in, const int* in_sizes, int n_in,
                              void* d_out, int out_size, void* d_ws, size_t ws_size,
                              hipStream_t stream)
{
    const float* mean   = (const float*)d_in[0];
    const float* cov    = (const float*)d_in[1];
    const float* Wd_in  = (const float*)d_in[2];
    const float* bd_in  = (const float*)d_in[3];
    const float* Wd_hid = (const float*)d_in[4];
    const float* bd_hid = (const float*)d_in[5];
    const float* Wd_out = (const float*)d_in[6];
    const float* bd_out = (const float*)d_in[7];
    const float* Wc_in  = (const float*)d_in[8];
    const float* bc_in  = (const float*)d_in[9];
    const float* Wc_hid = (const float*)d_in[10];
    const float* bc_hid = (const float*)d_in[11];
    const float* Wc_out = (const float*)d_in[12];
    const float* bc_out = (const float*)d_in[13];
    const int*   decay  = (const int*)d_in[14];

    _Float16* wws = (_Float16*)d_ws;
    float*    bws = (float*)((char*)d_ws + (size_t)W_TOTAL * 2);

    const int N = in_sizes[0] / 3;     // 262144 points

    const int prep_blocks = (PREP_TOTAL + 255) / 256;
    prep_kernel<<<prep_blocks, 256, 0, stream>>>(Wd_in, Wd_hid, Wd_out, Wc_in, Wc_hid, Wc_out,
                                                 bd_in, bd_hid, bd_out, bc_in, bc_hid, wws, bws);

    const int blocks = (N + 127) / 128;
    ffmlp_kernel<<<blocks, 256, 0, stream>>>(mean, cov, decay, wws, bws, bc_out, (float*)d_out, N);
}